// Round 11
// baseline (1594.716 us; speedup 1.0000x reference)
//
#include <hip/hip_runtime.h>
#include <hip/hip_bf16.h>

#define NN 32768
#define EE 262144
#define FD 128
#define NL 64
#define MROW 16     // nodes per block
#define SROW 132    // LDS row stride (ushorts)
#define NCH 4       // src chunks (8192 nodes = 2MB of g each; fits XCD L2)

typedef short v8s __attribute__((ext_vector_type(8)));
typedef float v4f __attribute__((ext_vector_type(4)));

__device__ __forceinline__ unsigned short f2bf(float x) {
    unsigned u = __builtin_bit_cast(unsigned, x);
    u += 0x7fffu + ((u >> 16) & 1u);
    return (unsigned short)(u >> 16);
}
__device__ __forceinline__ float bf2f(unsigned short h) {
    unsigned u = ((unsigned)h) << 16;
    return __builtin_bit_cast(float, u);
}
// accumulate 8 bf16 (packed in v8s) into acc[8]
__device__ __forceinline__ void acc8_bf16(float* acc, v8s r) {
    const int* d = (const int*)&r;
#pragma unroll
    for (int k = 0; k < 4; k++) {
        unsigned u = (unsigned)d[k];
        acc[2 * k]     += __builtin_bit_cast(float, u << 16);
        acc[2 * k + 1] += __builtin_bit_cast(float, u & 0xffff0000u);
    }
}

// ---------- setup ----------
// per-(node,chunk) degree count
__global__ __launch_bounds__(256) void k_deg(const int* __restrict__ src,
                                             const int* __restrict__ dst,
                                             int* __restrict__ cnt4) {
    int e = blockIdx.x * 256 + threadIdx.x;
    if (e < EE) {
        int s = src[e], d = dst[e];
        atomicAdd(&cnt4[d * NCH + (s >> 13)], 1);
    }
}

__global__ __launch_bounds__(256) void k_dinv(const int* __restrict__ cnt4,
                                              float* __restrict__ dinv) {
    int i = blockIdx.x * 256 + threadIdx.x;
    if (i < NN) {
        int4 c = *(const int4*)(cnt4 + i * 4);
        dinv[i] = rsqrtf((float)(c.x + c.y + c.z + c.w) + 1.0f);
    }
}

// exclusive scan of cnt4[4*NN] -> offsC[4*NN+1]; two-pass, 1024 thr x 128
__global__ __launch_bounds__(1024) void k_scan4(const int* __restrict__ cnt,
                                                int* __restrict__ offs) {
    __shared__ int wsum[16];
    int tid = threadIdx.x;
    int base = tid * 128;
    int s = 0;
    for (int i = 0; i < 128; i++) s += cnt[base + i];
    int lane = tid & 63, wv = tid >> 6;
    int x = s;
#pragma unroll
    for (int off = 1; off < 64; off <<= 1) {
        int y = __shfl_up(x, off);
        if (lane >= off) x += y;
    }
    if (lane == 63) wsum[wv] = x;
    __syncthreads();
    if (tid == 0) {
        int t = 0;
        for (int i = 0; i < 16; i++) { int v = wsum[i]; wsum[i] = t; t += v; }
        offs[4 * NN] = t;
    }
    __syncthreads();
    int run = wsum[wv] + x - s;   // exclusive prefix of this thread's range
    for (int i = 0; i < 128; i++) {
        offs[base + i] = run;
        run += cnt[base + i];
    }
}

__global__ __launch_bounds__(256) void k_fill(const int* __restrict__ src,
                                              const int* __restrict__ dst,
                                              const int* __restrict__ offsC,
                                              int* __restrict__ cursor4,
                                              int* __restrict__ col) {
    int e = blockIdx.x * 256 + threadIdx.x;
    if (e >= EE) return;
    int s = src[e], d = dst[e];
    int ch = s >> 13;
    int slot = atomicAdd(&cursor4[d * NCH + ch], 1);
    col[offsC[d * NCH + ch] + slot] = s;
}

// g0 = bf16(dinv[node] * x)
__global__ __launch_bounds__(256) void k_xcast(const float* __restrict__ x,
                                               const float* __restrict__ dinv,
                                               unsigned short* __restrict__ g) {
    int i = blockIdx.x * 256 + threadIdx.x;
    float di = dinv[(i * 8) >> 7];
    float4 a = *(const float4*)(x + (size_t)i * 8);
    float4 b = *(const float4*)(x + (size_t)i * 8 + 4);
    v8s o;
    o[0] = (short)f2bf(di * a.x); o[1] = (short)f2bf(di * a.y);
    o[2] = (short)f2bf(di * a.z); o[3] = (short)f2bf(di * a.w);
    o[4] = (short)f2bf(di * b.x); o[5] = (short)f2bf(di * b.y);
    o[6] = (short)f2bf(di * b.z); o[7] = (short)f2bf(di * b.w);
    *(v8s*)(g + (size_t)i * 8) = o;
}

// ---------- weight split: fp32 W -> bf16 hi/lo in MFMA B-fragment order ----
// [l][kstep(4)][ntile(8)][lane(64)][j(8)]; k = ks*32+(lane>>4)*8+j, n = nt*16+(lane&15)
__global__ __launch_bounds__(256) void k_wsplit(const float* __restrict__ W,
                                                unsigned short* __restrict__ Whi,
                                                unsigned short* __restrict__ Wlo) {
    int t = blockIdx.x * 256 + threadIdx.x;
    int l = t >> 11;
    int rem = t & 2047;
    int ks = rem >> 9;
    int rem2 = rem & 511;
    int nt = rem2 >> 6;
    int L = rem2 & 63;
    const float* Wl = W + (size_t)l * FD * FD;
    int kbase = ks * 32 + ((L >> 4) << 3);
    int n = nt * 16 + (L & 15);
    v8s hv, lv;
#pragma unroll
    for (int j = 0; j < 8; j++) {
        float w = Wl[(size_t)(kbase + j) * FD + n];
        unsigned short h = f2bf(w);
        hv[j] = (short)h;
        lv[j] = (short)f2bf(w - bf2f(h));
    }
    size_t o = (size_t)t * 8;
    *(v8s*)(Whi + o) = hv;
    *(v8s*)(Wlo + o) = lv;
}

// ---------- fused layer: g_out = dinv * relu( (dinv*(sum g)) @ W + b ) ----
// Block = 512 thr (8 waves), 16 nodes; wave handles 2 nodes. Gather runs
// CHUNK-MAJOR over 4 src-chunks (2MB each) so co-resident blocks share the
// same L2 window -> high hit rate (the L2-miss random path was ~90%
// saturated; R8/R10 falsified BW- and chain-latency models).
// 4 blocks/CU = 32 waves/CU. acc[2][8]=16 VGPR keeps us under the 64-VGPR
// budget at 8 waves/SIMD (R9 lesson: spills kill).
__global__ __launch_bounds__(512, 8) void k_layer(
        const unsigned short* __restrict__ g,
        const int* __restrict__ offsC,
        const int* __restrict__ col,
        const unsigned short* __restrict__ Whi,
        const unsigned short* __restrict__ Wlo,
        const float* __restrict__ dinv,
        const float* __restrict__ bias,
        unsigned short* __restrict__ gout,
        int last) {
    __shared__ unsigned short sA[MROW * SROW];
    __shared__ float sDinv[MROW];
    int tid = threadIdx.x;
    int lane = tid & 63;
    int w = tid >> 6;            // wave 0..7
    int row0 = blockIdx.x * MROW;
    int fg = lane >> 4;          // edge subgroup 0..3
    int fl = lane & 15;          // feature chunk (8 feats)
    const unsigned short* gf = g + fl * 8;

    if (tid < MROW) sDinv[tid] = dinv[row0 + tid];

    int nbase = row0 + w * 2;    // this wave's 2 nodes
    // lane-held segment boundaries: lane i (i<9) holds offsC[nbase*4 + i]
    int ovl = (lane < 2 * NCH + 1) ? offsC[nbase * NCH + lane] : 0;
    int B0 = __shfl(ovl, 0);
    int Etot = __shfl(ovl, 2 * NCH) - B0;

    float acc[2][8];
#pragma unroll
    for (int r = 0; r < 2; r++)
#pragma unroll
        for (int k = 0; k < 8; k++) acc[r][k] = 0.f;

    if (Etot <= 64) {
        // fast path: one coalesced col window covers both nodes, all chunks
        int c = (lane < Etot) ? col[B0 + lane] : 0;
#pragma unroll
        for (int ch = 0; ch < NCH; ch++) {       // CHUNK-MAJOR
#pragma unroll
            for (int r = 0; r < 2; r++) {
                int s = __shfl(ovl, r * NCH + ch) - B0;
                int e = __shfl(ovl, r * NCH + ch + 1) - B0;
                for (int j = s; j < e; j += 8) {
                    int e0 = j + fg, e1 = j + 4 + fg;
                    int s0 = __shfl(c, e0 & 63);
                    int s1 = __shfl(c, e1 & 63);
                    bool p0 = e0 < e, p1 = e1 < e;
                    v8s r0, r1;
                    if (p0) r0 = *(const v8s*)(gf + (size_t)s0 * FD);
                    if (p1) r1 = *(const v8s*)(gf + (size_t)s1 * FD);
                    if (p0) acc8_bf16(acc[r], r0);
                    if (p1) acc8_bf16(acc[r], r1);
                }
            }
        }
    } else {
        // rare fallback: per-node windows over the node's full (contiguous)
        // range; chunk order irrelevant for correctness.
        for (int r = 0; r < 2; r++) {
            int b = __shfl(ovl, r * NCH);
            int e = __shfl(ovl, r * NCH + NCH);
            int deg = e - b;
            for (int base = 0; base < deg; base += 64) {
                int n = min(deg - base, 64);
                int c = (lane < n) ? col[b + base + lane] : 0;
                for (int j = 0; j < n; j += 8) {
                    int e0 = j + fg, e1 = j + 4 + fg;
                    int s0 = __shfl(c, e0 & 63);
                    int s1 = __shfl(c, e1 & 63);
                    bool p0 = e0 < n, p1 = e1 < n;
                    v8s r0, r1;
                    if (p0) r0 = *(const v8s*)(gf + (size_t)s0 * FD);
                    if (p1) r1 = *(const v8s*)(gf + (size_t)s1 * FD);
                    if (p0) acc8_bf16(acc[r], r0);
                    if (p1) acc8_bf16(acc[r], r1);
                }
            }
        }
    }

    // reduce subgroups, add self loop, scale, write to LDS
#pragma unroll
    for (int r = 0; r < 2; r++) {
        int node = nbase + r;
#pragma unroll
        for (int k = 0; k < 8; k++) {
            acc[r][k] += __shfl_xor(acc[r][k], 16);
            acc[r][k] += __shfl_xor(acc[r][k], 32);
        }
        v8s sv = *(const v8s*)(gf + (size_t)node * FD);
        acc8_bf16(acc[r], sv);      // after reduce: added exactly once
        if (fg == 0) {
            float di = dinv[node];
            unsigned pk[4];
#pragma unroll
            for (int k = 0; k < 4; k++) {
                pk[k] = (unsigned)f2bf(di * acc[r][2 * k]) |
                        ((unsigned)f2bf(di * acc[r][2 * k + 1]) << 16);
            }
            *(v8s*)&sA[(w * 2 + r) * SROW + fl * 8] = *(v8s*)pk;
        }
    }
    __syncthreads();

    // phase 2: 16x128 @ 128x128 MFMA; wave w covers cols w*16..+15
    v4f a0 = (v4f){0.f, 0.f, 0.f, 0.f};
#pragma unroll
    for (int ks = 0; ks < 4; ks++) {
        v8s ah = *(const v8s*)&sA[(lane & 15) * SROW + ks * 32 + ((lane >> 4) << 3)];
        size_t bo = ((size_t)(ks * 8 + w) * 64 + lane) * 8;
        v8s bh = *(const v8s*)(Whi + bo);
        v8s bl = *(const v8s*)(Wlo + bo);
        a0 = __builtin_amdgcn_mfma_f32_16x16x32_bf16(ah, bh, a0, 0, 0, 0);
        a0 = __builtin_amdgcn_mfma_f32_16x16x32_bf16(ah, bl, a0, 0, 0, 0);
    }
    __syncthreads();  // before reusing sA

    // epilogue: bias + relu (+ dinv unless last), LDS bounce, coalesced store
    float bb = bias[w * 16 + (lane & 15)];
    int col_l = w * 16 + (lane & 15);
#pragma unroll
    for (int rg = 0; rg < 4; rg++) {
        int row_l = ((lane >> 4) << 2) + rg;
        float v = fmaxf(a0[rg] + bb, 0.f);
        if (!last) v *= sDinv[row_l];
        sA[row_l * SROW + col_l] = f2bf(v);
    }
    __syncthreads();
    int orow = tid >> 5;            // 0..15
    int ocol = (tid & 31) * 4;      // 0..124
    *(ushort4*)(gout + (size_t)(row0 + orow) * FD + ocol) =
        *(const ushort4*)&sA[orow * SROW + ocol];
}

// ---------- residual + classifier: out = (h + x) @ cls_w + cls_b ----------
__global__ __launch_bounds__(256) void k_cls(const unsigned short* __restrict__ h,
                                             const float* __restrict__ x,
                                             const float* __restrict__ cw,
                                             const float* __restrict__ cb,
                                             float* __restrict__ out) {
    int gw = (blockIdx.x * 256 + threadIdx.x) >> 6;
    int lane = threadIdx.x & 63;
    size_t o = (size_t)gw * FD + lane * 2;
    ushort2 hh = *(const ushort2*)(h + o);
    float2 xv = *(const float2*)(x + o);
    float sx = bf2f(hh.x) + xv.x;
    float sy = bf2f(hh.y) + xv.y;
    float4 w0 = *(const float4*)(cw + (lane * 2) * 4);
    float4 w1 = *(const float4*)(cw + (lane * 2 + 1) * 4);
    float p0 = sx * w0.x + sy * w1.x;
    float p1 = sx * w0.y + sy * w1.y;
    float p2 = sx * w0.z + sy * w1.z;
    float p3 = sx * w0.w + sy * w1.w;
#pragma unroll
    for (int off = 32; off > 0; off >>= 1) {
        p0 += __shfl_down(p0, off);
        p1 += __shfl_down(p1, off);
        p2 += __shfl_down(p2, off);
        p3 += __shfl_down(p3, off);
    }
    if (lane == 0) {
        float4 r2 = make_float4(p0 + cb[0], p1 + cb[1], p2 + cb[2], p3 + cb[3]);
        *(float4*)(out + (size_t)gw * 4) = r2;
    }
}

extern "C" void kernel_launch(void* const* d_in, const int* in_sizes, int n_in,
                              void* d_out, int out_size, void* d_ws, size_t ws_size,
                              hipStream_t stream) {
    const float* x       = (const float*)d_in[0];
    const int* ei        = (const int*)d_in[1];       // [2][EE], int32
    const float* weights = (const float*)d_in[2];
    const float* biases  = (const float*)d_in[3];
    const float* cls_w   = (const float*)d_in[4];
    const float* cls_b   = (const float*)d_in[5];
    float* out = (float*)d_out;

    char* ws = (char*)d_ws;
    size_t off = 0;
    auto alloc = [&](size_t bytes) -> void* {
        off = (off + 255) & ~(size_t)255;
        void* p = ws + off;
        off += bytes;
        return p;
    };
    int*   cnt4    = (int*)alloc((size_t)NN * NCH * 4);
    int*   cursor4 = (int*)alloc((size_t)NN * NCH * 4);
    float* dinv    = (float*)alloc((size_t)NN * 4);
    int*   offsC   = (int*)alloc(((size_t)NN * NCH + 8) * 4);
    int*   col     = (int*)alloc((size_t)EE * 4);
    unsigned short* Whi = (unsigned short*)alloc((size_t)NL * FD * FD * 2);
    unsigned short* Wlo = (unsigned short*)alloc((size_t)NL * FD * FD * 2);
    unsigned short* h0  = (unsigned short*)alloc((size_t)NN * FD * 2);
    unsigned short* h1  = (unsigned short*)alloc((size_t)NN * FD * 2);

    const int* srcv = ei;
    const int* dstv = ei + EE;

    hipMemsetAsync(cnt4, 0, (size_t)NN * NCH * 4, stream);
    hipMemsetAsync(cursor4, 0, (size_t)NN * NCH * 4, stream);
    k_deg<<<EE / 256, 256, 0, stream>>>(srcv, dstv, cnt4);
    k_dinv<<<NN / 256, 256, 0, stream>>>(cnt4, dinv);
    k_scan4<<<1, 1024, 0, stream>>>(cnt4, offsC);
    k_fill<<<EE / 256, 256, 0, stream>>>(srcv, dstv, offsC, cursor4, col);
    k_wsplit<<<NL * 2048 / 256, 256, 0, stream>>>(weights, Whi, Wlo);
    k_xcast<<<NN * FD / 2048, 256, 0, stream>>>(x, dinv, h1);  // g0 in h1

    const unsigned short* gin = h1;
    for (int l = 0; l < NL; l++) {
        unsigned short* gout = (l & 1) ? h1 : h0;
        k_layer<<<NN / MROW, 512, 0, stream>>>(gin, offsC, col,
                                               Whi + (size_t)l * FD * FD,
                                               Wlo + (size_t)l * FD * FD,
                                               dinv, biases + (size_t)l * FD,
                                               gout, l == NL - 1);
        gin = gout;
    }
    k_cls<<<NN * 64 / 256, 256, 0, stream>>>(gin, x, cls_w, cls_b, out);
}

// Round 12
// 1159.829 us; speedup vs baseline: 1.3750x; 1.3750x over previous
//
#include <hip/hip_runtime.h>
#include <hip/hip_bf16.h>

#define NN 32768
#define EE 262144
#define FD 128
#define NL 64
#define MROW 16     // nodes per block — 2048 blocks, 8/CU, 32 waves/CU (proven best)
#define SROW 132    // LDS row stride (ushorts)

typedef short v8s __attribute__((ext_vector_type(8)));
typedef float v4f __attribute__((ext_vector_type(4)));

__device__ __forceinline__ unsigned short f2bf(float x) {
    unsigned u = __builtin_bit_cast(unsigned, x);
    u += 0x7fffu + ((u >> 16) & 1u);
    return (unsigned short)(u >> 16);
}
__device__ __forceinline__ float bf2f(unsigned short h) {
    unsigned u = ((unsigned)h) << 16;
    return __builtin_bit_cast(float, u);
}
// accumulate 8 bf16 (packed in v8s) into acc[8]
__device__ __forceinline__ void acc8_bf16(float* acc, v8s r) {
    const int* d = (const int*)&r;
#pragma unroll
    for (int k = 0; k < 4; k++) {
        unsigned u = (unsigned)d[k];
        acc[2 * k]     += __builtin_bit_cast(float, u << 16);
        acc[2 * k + 1] += __builtin_bit_cast(float, u & 0xffff0000u);
    }
}

// ---------- setup ----------
__global__ __launch_bounds__(256) void k_deg(const int* __restrict__ dst,
                                             int* __restrict__ cnt) {
    int e = blockIdx.x * 256 + threadIdx.x;
    if (e < EE) atomicAdd(&cnt[dst[e]], 1);
}

__global__ __launch_bounds__(256) void k_dinv(const int* __restrict__ cnt,
                                              float* __restrict__ dinv) {
    int i = blockIdx.x * 256 + threadIdx.x;
    if (i < NN) dinv[i] = rsqrtf((float)cnt[i] + 1.0f);
}

__global__ __launch_bounds__(1024) void k_scan(const int* __restrict__ cnt,
                                               int* __restrict__ offs) {
    __shared__ int wsum[16];
    int tid = threadIdx.x;
    int base = tid * 32;
    int local[32];
    int s = 0;
#pragma unroll
    for (int i = 0; i < 32; i++) { local[i] = s; s += cnt[base + i]; }
    int lane = tid & 63, wv = tid >> 6;
    int x = s;
#pragma unroll
    for (int off = 1; off < 64; off <<= 1) {
        int y = __shfl_up(x, off);
        if (lane >= off) x += y;
    }
    if (lane == 63) wsum[wv] = x;
    __syncthreads();
    if (tid == 0) {
        int t = 0;
        for (int i = 0; i < 16; i++) { int v = wsum[i]; wsum[i] = t; t += v; }
        offs[NN] = t;
    }
    __syncthreads();
    int excl = wsum[wv] + x - s;
#pragma unroll
    for (int i = 0; i < 32; i++) offs[base + i] = excl + local[i];
}

__global__ __launch_bounds__(256) void k_fill(const int* __restrict__ src,
                                              const int* __restrict__ dst,
                                              const int* __restrict__ offs,
                                              int* __restrict__ cursor,
                                              int* __restrict__ col) {
    int e = blockIdx.x * 256 + threadIdx.x;
    if (e >= EE) return;
    int s = src[e], d = dst[e];
    int slot = atomicAdd(&cursor[d], 1);
    col[offs[d] + slot] = s;
}

// g0 = bf16(dinv[node] * x)
__global__ __launch_bounds__(256) void k_xcast(const float* __restrict__ x,
                                               const float* __restrict__ dinv,
                                               unsigned short* __restrict__ g) {
    int i = blockIdx.x * 256 + threadIdx.x;
    float di = dinv[(i * 8) >> 7];
    float4 a = *(const float4*)(x + (size_t)i * 8);
    float4 b = *(const float4*)(x + (size_t)i * 8 + 4);
    v8s o;
    o[0] = (short)f2bf(di * a.x); o[1] = (short)f2bf(di * a.y);
    o[2] = (short)f2bf(di * a.z); o[3] = (short)f2bf(di * a.w);
    o[4] = (short)f2bf(di * b.x); o[5] = (short)f2bf(di * b.y);
    o[6] = (short)f2bf(di * b.z); o[7] = (short)f2bf(di * b.w);
    *(v8s*)(g + (size_t)i * 8) = o;
}

// ---------- weight cast: fp32 W -> bf16 (single) in MFMA B-fragment order --
// [l][kstep(4)][ntile(8)][lane(64)][j(8)]; k = ks*32+(lane>>4)*8+j, n = nt*16+(lane&15)
// bf16-only (no lo part): halves the per-launch W stream 268->134 MB so g
// stays L3-resident (R11 profile: gather was HBM-fed because the hi+lo W
// stream ~= L3 size evicted g every launch).
__global__ __launch_bounds__(256) void k_wcast(const float* __restrict__ W,
                                               unsigned short* __restrict__ Whi) {
    int t = blockIdx.x * 256 + threadIdx.x;
    int l = t >> 11;
    int rem = t & 2047;
    int ks = rem >> 9;
    int rem2 = rem & 511;
    int nt = rem2 >> 6;
    int L = rem2 & 63;
    const float* Wl = W + (size_t)l * FD * FD;
    int kbase = ks * 32 + ((L >> 4) << 3);
    int n = nt * 16 + (L & 15);
    v8s hv;
#pragma unroll
    for (int j = 0; j < 8; j++)
        hv[j] = (short)f2bf(Wl[(size_t)(kbase + j) * FD + n]);
    *(v8s*)(Whi + (size_t)t * 8) = hv;
}

// ---------- fused layer: g_out = dinv * relu( (dinv*(sum g)) @ W + b ) ----
// R10 structure (best): 16 lanes/edge x 4 edge-groups, hoisted offs + single
// 64-wide col window for the wave's 4 contiguous nodes. Phase 2: M=16 MFMA,
// W bf16-only (1 MFMA per fragment).
__global__ __launch_bounds__(256, 8) void k_layer(
        const unsigned short* __restrict__ g,
        const int* __restrict__ offs,
        const int* __restrict__ col,
        const unsigned short* __restrict__ Whi,
        const float* __restrict__ dinv,
        const float* __restrict__ bias,
        unsigned short* __restrict__ gout,
        int last) {
    __shared__ unsigned short sA[MROW * SROW];
    __shared__ float sDinv[MROW];
    int tid = threadIdx.x;
    int lane = tid & 63;
    int w = tid >> 6;
    int row0 = blockIdx.x * MROW;
    int fg = lane >> 4;        // edge subgroup 0..3
    int fl = lane & 15;        // feature chunk (8 feats)
    const unsigned short* gf = g + fl * 8;

    if (tid < MROW) sDinv[tid] = dinv[row0 + tid];

    int nbase = row0 + w * 4;                      // multiple of 4 -> aligned
    int4 ov = *(const int4*)(offs + nbase);
    int o4 = offs[nbase + 4];
    int B0 = ov.x;
    int Etot = o4 - B0;

    if (Etot <= 64) {
        // fast path: one coalesced col window covers all 4 nodes
        int c = (lane < Etot) ? col[B0 + lane] : 0;
        int seg[5];
        seg[0] = 0; seg[1] = ov.y - B0; seg[2] = ov.z - B0;
        seg[3] = ov.w - B0; seg[4] = Etot;
#pragma unroll
        for (int r = 0; r < 4; r++) {
            int node = nbase + r;
            int s = seg[r], e = seg[r + 1];
            v8s selfv = *(const v8s*)(gf + (size_t)node * FD);  // early, indep
            float acc[8];
#pragma unroll
            for (int k = 0; k < 8; k++) acc[k] = 0.f;
            for (int j = s; j < e; j += 8) {
                int e0 = j + fg, e1 = j + 4 + fg;
                int s0 = __shfl(c, e0 & 63);
                int s1 = __shfl(c, e1 & 63);
                bool p0 = e0 < e, p1 = e1 < e;
                v8s r0, r1;
                if (p0) r0 = *(const v8s*)(gf + (size_t)s0 * FD);
                if (p1) r1 = *(const v8s*)(gf + (size_t)s1 * FD);
                if (p0) acc8_bf16(acc, r0);
                if (p1) acc8_bf16(acc, r1);
            }
#pragma unroll
            for (int k = 0; k < 8; k++) {
                acc[k] += __shfl_xor(acc[k], 16);
                acc[k] += __shfl_xor(acc[k], 32);
            }
            acc8_bf16(acc, selfv);   // self loop (same value across fg groups)
            if (fg == 0) {
                float di = dinv[node];
                unsigned pk[4];
#pragma unroll
                for (int k = 0; k < 4; k++) {
                    pk[k] = (unsigned)f2bf(di * acc[2 * k]) |
                            ((unsigned)f2bf(di * acc[2 * k + 1]) << 16);
                }
                *(v8s*)&sA[(w * 4 + r) * SROW + fl * 8] = *(v8s*)pk;
            }
        }
    } else {
        // rare path: per-node col loads, any degree
        for (int r = 0; r < 4; r++) {
            int nloc = w * 4 + r;
            int node = row0 + nloc;
            float acc[8];
#pragma unroll
            for (int k = 0; k < 8; k++) acc[k] = 0.f;
            int b = offs[node], e = offs[node + 1];
            int deg = e - b;
            for (int base = 0; base < deg; base += 64) {
                int n = min(deg - base, 64);
                int c = (lane < n) ? col[b + base + lane] : 0;
                for (int j = 0; j < n; j += 8) {
                    int e0 = j + fg, e1 = j + 4 + fg;
                    int s0 = __shfl(c, e0 & 63);
                    int s1 = __shfl(c, e1 & 63);
                    bool p0 = e0 < n, p1 = e1 < n;
                    v8s r0, r1;
                    if (p0) r0 = *(const v8s*)(gf + (size_t)s0 * FD);
                    if (p1) r1 = *(const v8s*)(gf + (size_t)s1 * FD);
                    if (p0) acc8_bf16(acc, r0);
                    if (p1) acc8_bf16(acc, r1);
                }
            }
#pragma unroll
            for (int k = 0; k < 8; k++) {
                acc[k] += __shfl_xor(acc[k], 16);
                acc[k] += __shfl_xor(acc[k], 32);
            }
            v8s sv = *(const v8s*)(gf + (size_t)node * FD);
            acc8_bf16(acc, sv);
            if (fg == 0) {
                float di = dinv[node];
                unsigned pk[4];
#pragma unroll
                for (int k = 0; k < 4; k++) {
                    pk[k] = (unsigned)f2bf(di * acc[2 * k]) |
                            ((unsigned)f2bf(di * acc[2 * k + 1]) << 16);
                }
                *(v8s*)&sA[nloc * SROW + fl * 8] = *(v8s*)pk;
            }
        }
    }
    __syncthreads();

    // phase 2: 16x128 @ 128x128 MFMA (A from LDS, W bf16 from L2)
    v4f a0 = (v4f){0.f, 0.f, 0.f, 0.f};
    v4f a1 = (v4f){0.f, 0.f, 0.f, 0.f};
#pragma unroll
    for (int ks = 0; ks < 4; ks++) {
        v8s ah = *(const v8s*)&sA[(lane & 15) * SROW + ks * 32 + ((lane >> 4) << 3)];
        size_t bo0 = ((size_t)(ks * 8 + w * 2) * 64 + lane) * 8;
        size_t bo1 = ((size_t)(ks * 8 + w * 2 + 1) * 64 + lane) * 8;
        v8s bh0 = *(const v8s*)(Whi + bo0);
        v8s bh1 = *(const v8s*)(Whi + bo1);
        a0 = __builtin_amdgcn_mfma_f32_16x16x32_bf16(ah, bh0, a0, 0, 0, 0);
        a1 = __builtin_amdgcn_mfma_f32_16x16x32_bf16(ah, bh1, a1, 0, 0, 0);
    }
    __syncthreads();  // before reusing sA

    // epilogue: bias + relu (+ dinv unless last), LDS bounce, coalesced store
    float bb0 = bias[w * 32 + (lane & 15)];
    float bb1 = bias[w * 32 + 16 + (lane & 15)];
#pragma unroll
    for (int nt = 0; nt < 2; nt++) {
        int col_l = w * 32 + nt * 16 + (lane & 15);
        float bb = nt ? bb1 : bb0;
        v4f a = nt ? a1 : a0;
#pragma unroll
        for (int rg = 0; rg < 4; rg++) {
            int row_l = ((lane >> 4) << 2) + rg;
            float v = fmaxf(a[rg] + bb, 0.f);
            if (!last) v *= sDinv[row_l];
            sA[row_l * SROW + col_l] = f2bf(v);
        }
    }
    __syncthreads();
    int orow = tid >> 4;
    int ocol = (tid & 15) * 8;
    *(v8s*)(gout + (size_t)(row0 + orow) * FD + ocol) =
        *(const v8s*)&sA[orow * SROW + ocol];
}

// ---------- residual + classifier: out = (h + x) @ cls_w + cls_b ----------
__global__ __launch_bounds__(256) void k_cls(const unsigned short* __restrict__ h,
                                             const float* __restrict__ x,
                                             const float* __restrict__ cw,
                                             const float* __restrict__ cb,
                                             float* __restrict__ out) {
    int gw = (blockIdx.x * 256 + threadIdx.x) >> 6;
    int lane = threadIdx.x & 63;
    size_t o = (size_t)gw * FD + lane * 2;
    ushort2 hh = *(const ushort2*)(h + o);
    float2 xv = *(const float2*)(x + o);
    float sx = bf2f(hh.x) + xv.x;
    float sy = bf2f(hh.y) + xv.y;
    float4 w0 = *(const float4*)(cw + (lane * 2) * 4);
    float4 w1 = *(const float4*)(cw + (lane * 2 + 1) * 4);
    float p0 = sx * w0.x + sy * w1.x;
    float p1 = sx * w0.y + sy * w1.y;
    float p2 = sx * w0.z + sy * w1.z;
    float p3 = sx * w0.w + sy * w1.w;
#pragma unroll
    for (int off = 32; off > 0; off >>= 1) {
        p0 += __shfl_down(p0, off);
        p1 += __shfl_down(p1, off);
        p2 += __shfl_down(p2, off);
        p3 += __shfl_down(p3, off);
    }
    if (lane == 0) {
        float4 r2 = make_float4(p0 + cb[0], p1 + cb[1], p2 + cb[2], p3 + cb[3]);
        *(float4*)(out + (size_t)gw * 4) = r2;
    }
}

extern "C" void kernel_launch(void* const* d_in, const int* in_sizes, int n_in,
                              void* d_out, int out_size, void* d_ws, size_t ws_size,
                              hipStream_t stream) {
    const float* x       = (const float*)d_in[0];
    const int* ei        = (const int*)d_in[1];       // [2][EE], int32
    const float* weights = (const float*)d_in[2];
    const float* biases  = (const float*)d_in[3];
    const float* cls_w   = (const float*)d_in[4];
    const float* cls_b   = (const float*)d_in[5];
    float* out = (float*)d_out;

    char* ws = (char*)d_ws;
    size_t off = 0;
    auto alloc = [&](size_t bytes) -> void* {
        off = (off + 255) & ~(size_t)255;
        void* p = ws + off;
        off += bytes;
        return p;
    };
    int*   cnt    = (int*)alloc((size_t)NN * 4);
    int*   cursor = (int*)alloc((size_t)NN * 4);
    float* dinv   = (float*)alloc((size_t)NN * 4);
    int*   offs   = (int*)alloc((size_t)(NN + 1) * 4);
    int*   col    = (int*)alloc((size_t)EE * 4);
    unsigned short* Whi = (unsigned short*)alloc((size_t)NL * FD * FD * 2);
    unsigned short* h0  = (unsigned short*)alloc((size_t)NN * FD * 2);
    unsigned short* h1  = (unsigned short*)alloc((size_t)NN * FD * 2);

    const int* srcv = ei;
    const int* dstv = ei + EE;

    hipMemsetAsync(cnt, 0, (size_t)NN * 4, stream);
    hipMemsetAsync(cursor, 0, (size_t)NN * 4, stream);
    k_deg<<<EE / 256, 256, 0, stream>>>(dstv, cnt);
    k_dinv<<<NN / 256, 256, 0, stream>>>(cnt, dinv);
    k_scan<<<1, 1024, 0, stream>>>(cnt, offs);
    k_fill<<<EE / 256, 256, 0, stream>>>(srcv, dstv, offs, cursor, col);
    k_wcast<<<NL * 2048 / 256, 256, 0, stream>>>(weights, Whi);
    k_xcast<<<NN * FD / 2048, 256, 0, stream>>>(x, dinv, h1);  // g0 in h1

    const unsigned short* gin = h1;
    for (int l = 0; l < NL; l++) {
        unsigned short* gout = (l & 1) ? h1 : h0;
        k_layer<<<NN / MROW, 256, 0, stream>>>(gin, offs, col,
                                               Whi + (size_t)l * FD * FD,
                                               dinv, biases + (size_t)l * FD,
                                               gout, l == NL - 1);
        gin = gout;
    }
    k_cls<<<NN * 64 / 256, 256, 0, stream>>>(gin, x, cls_w, cls_b, out);
}

// Round 13
// 1106.462 us; speedup vs baseline: 1.4413x; 1.0482x over previous
//
#include <hip/hip_runtime.h>
#include <hip/hip_bf16.h>

#define NN 32768
#define EE 262144
#define FD 128
#define NL 64
#define MROW 16     // nodes per block — 2048 blocks, 8/CU, 32 waves/CU
#define SROW 132    // LDS row stride (ushorts)

typedef short v8s __attribute__((ext_vector_type(8)));
typedef float v4f __attribute__((ext_vector_type(4)));

__device__ __forceinline__ unsigned short f2bf(float x) {
    unsigned u = __builtin_bit_cast(unsigned, x);
    u += 0x7fffu + ((u >> 16) & 1u);
    return (unsigned short)(u >> 16);
}
__device__ __forceinline__ float bf2f(unsigned short h) {
    unsigned u = ((unsigned)h) << 16;
    return __builtin_bit_cast(float, u);
}
// accumulate 8 bf16 (packed in v8s) into acc[8]
__device__ __forceinline__ void acc8_bf16(float* acc, v8s r) {
    const int* d = (const int*)&r;
#pragma unroll
    for (int k = 0; k < 4; k++) {
        unsigned u = (unsigned)d[k];
        acc[2 * k]     += __builtin_bit_cast(float, u << 16);
        acc[2 * k + 1] += __builtin_bit_cast(float, u & 0xffff0000u);
    }
}

// ---------- setup ----------
__global__ __launch_bounds__(256) void k_deg(const int* __restrict__ dst,
                                             int* __restrict__ cnt) {
    int e = blockIdx.x * 256 + threadIdx.x;
    if (e < EE) atomicAdd(&cnt[dst[e]], 1);
}

__global__ __launch_bounds__(256) void k_dinv(const int* __restrict__ cnt,
                                              float* __restrict__ dinv) {
    int i = blockIdx.x * 256 + threadIdx.x;
    if (i < NN) dinv[i] = rsqrtf((float)cnt[i] + 1.0f);
}

__global__ __launch_bounds__(1024) void k_scan(const int* __restrict__ cnt,
                                               int* __restrict__ offs) {
    __shared__ int wsum[16];
    int tid = threadIdx.x;
    int base = tid * 32;
    int local[32];
    int s = 0;
#pragma unroll
    for (int i = 0; i < 32; i++) { local[i] = s; s += cnt[base + i]; }
    int lane = tid & 63, wv = tid >> 6;
    int x = s;
#pragma unroll
    for (int off = 1; off < 64; off <<= 1) {
        int y = __shfl_up(x, off);
        if (lane >= off) x += y;
    }
    if (lane == 63) wsum[wv] = x;
    __syncthreads();
    if (tid == 0) {
        int t = 0;
        for (int i = 0; i < 16; i++) { int v = wsum[i]; wsum[i] = t; t += v; }
        offs[NN] = t;
    }
    __syncthreads();
    int excl = wsum[wv] + x - s;
#pragma unroll
    for (int i = 0; i < 32; i++) offs[base + i] = excl + local[i];
}

__global__ __launch_bounds__(256) void k_fill(const int* __restrict__ src,
                                              const int* __restrict__ dst,
                                              const int* __restrict__ offs,
                                              int* __restrict__ cursor,
                                              int* __restrict__ col) {
    int e = blockIdx.x * 256 + threadIdx.x;
    if (e >= EE) return;
    int s = src[e], d = dst[e];
    int slot = atomicAdd(&cursor[d], 1);
    col[offs[d] + slot] = s;
}

// g0 = bf16(dinv[node] * x)
__global__ __launch_bounds__(256) void k_xcast(const float* __restrict__ x,
                                               const float* __restrict__ dinv,
                                               unsigned short* __restrict__ g) {
    int i = blockIdx.x * 256 + threadIdx.x;
    float di = dinv[(i * 8) >> 7];
    float4 a = *(const float4*)(x + (size_t)i * 8);
    float4 b = *(const float4*)(x + (size_t)i * 8 + 4);
    v8s o;
    o[0] = (short)f2bf(di * a.x); o[1] = (short)f2bf(di * a.y);
    o[2] = (short)f2bf(di * a.z); o[3] = (short)f2bf(di * a.w);
    o[4] = (short)f2bf(di * b.x); o[5] = (short)f2bf(di * b.y);
    o[6] = (short)f2bf(di * b.z); o[7] = (short)f2bf(di * b.w);
    *(v8s*)(g + (size_t)i * 8) = o;
}

// ---------- weight cast: fp32 W -> bf16 in MFMA B-fragment order ----------
// [l][kstep(4)][ntile(8)][lane(64)][j(8)]; k = ks*32+(lane>>4)*8+j, n = nt*16+(lane&15)
__global__ __launch_bounds__(256) void k_wcast(const float* __restrict__ W,
                                               unsigned short* __restrict__ Whi) {
    int t = blockIdx.x * 256 + threadIdx.x;
    int l = t >> 11;
    int rem = t & 2047;
    int ks = rem >> 9;
    int rem2 = rem & 511;
    int nt = rem2 >> 6;
    int L = rem2 & 63;
    const float* Wl = W + (size_t)l * FD * FD;
    int kbase = ks * 32 + ((L >> 4) << 3);
    int n = nt * 16 + (L & 15);
    v8s hv;
#pragma unroll
    for (int j = 0; j < 8; j++)
        hv[j] = (short)f2bf(Wl[(size_t)(kbase + j) * FD + n]);
    *(v8s*)(Whi + (size_t)t * 8) = hv;
}

// ---------- fused layer: g_out = dinv * relu( (dinv*(sum g)) @ W + b ) ----
// Phase 1 (NEW): one 16-lane group per node (16 lanes x 16B = the full
// 256B row). Node-private per-lane acc -> NO cross-lane reduce, no fg==0
// serialization; 4-deep unrolled predicated gather keeps 4 loads in
// flight/wave continuously (R12 post-mortem: issue duty cycle, not memory
// service, limited throughput at ~15 B/cyc/CU).
__global__ __launch_bounds__(256, 8) void k_layer(
        const unsigned short* __restrict__ g,
        const int* __restrict__ offs,
        const int* __restrict__ col,
        const unsigned short* __restrict__ Whi,
        const float* __restrict__ dinv,
        const float* __restrict__ bias,
        unsigned short* __restrict__ gout,
        int last) {
    __shared__ unsigned short sA[MROW * SROW];
    __shared__ float sDinv[MROW];
    int tid = threadIdx.x;
    int lane = tid & 63;
    int w = tid >> 6;
    int row0 = blockIdx.x * MROW;
    int fg = lane >> 4;        // node subgroup 0..3 (one node per group)
    int fl = lane & 15;        // feature chunk (8 feats = 16B)
    const unsigned short* gf = g + fl * 8;

    if (tid < MROW) sDinv[tid] = dinv[row0 + tid];

    int nbase = row0 + w * 4;                      // multiple of 4 -> aligned
    int4 ov = *(const int4*)(offs + nbase);
    int o4 = offs[nbase + 4];
    int B0 = ov.x;
    int Etot = o4 - B0;

    if (Etot <= 64) {
        // fast path: one coalesced col window covers all 4 nodes
        int c = (lane < Etot) ? col[B0 + lane] : 0;
        int node = nbase + fg;
        int sg = ((fg == 0) ? ov.x : (fg == 1) ? ov.y : (fg == 2) ? ov.z : ov.w) - B0;
        int eg = ((fg == 0) ? ov.y : (fg == 1) ? ov.z : (fg == 2) ? ov.w : o4) - B0;
        int len = eg - sg;
        int m = max(len, __shfl_xor(len, 16));
        m = max(m, __shfl_xor(m, 32));      // max deg over the 4 groups
        v8s selfv = *(const v8s*)(gf + (size_t)node * FD);  // early, indep
        float acc[8];
#pragma unroll
        for (int k = 0; k < 8; k++) acc[k] = 0.f;
        for (int j = 0; j < m; j += 4) {
            int i0 = sg + j, i1 = sg + j + 1, i2 = sg + j + 2, i3 = sg + j + 3;
            bool p0 = i0 < eg, p1 = i1 < eg, p2 = i2 < eg, p3 = i3 < eg;
            int s0 = __shfl(c, i0 & 63);
            int s1 = __shfl(c, i1 & 63);
            int s2 = __shfl(c, i2 & 63);
            int s3 = __shfl(c, i3 & 63);
            v8s r0, r1, r2, r3;
            if (p0) r0 = *(const v8s*)(gf + (size_t)s0 * FD);
            if (p1) r1 = *(const v8s*)(gf + (size_t)s1 * FD);
            if (p2) r2 = *(const v8s*)(gf + (size_t)s2 * FD);
            if (p3) r3 = *(const v8s*)(gf + (size_t)s3 * FD);
            if (p0) acc8_bf16(acc, r0);
            if (p1) acc8_bf16(acc, r1);
            if (p2) acc8_bf16(acc, r2);
            if (p3) acc8_bf16(acc, r3);
        }
        acc8_bf16(acc, selfv);   // self loop
        float di = dinv[node];
        unsigned pk[4];
#pragma unroll
        for (int k = 0; k < 4; k++) {
            pk[k] = (unsigned)f2bf(di * acc[2 * k]) |
                    ((unsigned)f2bf(di * acc[2 * k + 1]) << 16);
        }
        *(v8s*)&sA[(w * 4 + fg) * SROW + fl * 8] = *(v8s*)pk;  // all lanes write
    } else {
        // rare path (R12 verbatim): per-node col loads, any degree
        for (int r = 0; r < 4; r++) {
            int nloc = w * 4 + r;
            int node = row0 + nloc;
            float acc[8];
#pragma unroll
            for (int k = 0; k < 8; k++) acc[k] = 0.f;
            int b = offs[node], e = offs[node + 1];
            int deg = e - b;
            for (int base = 0; base < deg; base += 64) {
                int n = min(deg - base, 64);
                int c = (lane < n) ? col[b + base + lane] : 0;
                for (int j = 0; j < n; j += 8) {
                    int e0 = j + fg, e1 = j + 4 + fg;
                    int s0 = __shfl(c, e0 & 63);
                    int s1 = __shfl(c, e1 & 63);
                    bool p0 = e0 < n, p1 = e1 < n;
                    v8s r0, r1;
                    if (p0) r0 = *(const v8s*)(gf + (size_t)s0 * FD);
                    if (p1) r1 = *(const v8s*)(gf + (size_t)s1 * FD);
                    if (p0) acc8_bf16(acc, r0);
                    if (p1) acc8_bf16(acc, r1);
                }
            }
#pragma unroll
            for (int k = 0; k < 8; k++) {
                acc[k] += __shfl_xor(acc[k], 16);
                acc[k] += __shfl_xor(acc[k], 32);
            }
            v8s sv = *(const v8s*)(gf + (size_t)node * FD);
            acc8_bf16(acc, sv);
            if (fg == 0) {
                float di = dinv[node];
                unsigned pk[4];
#pragma unroll
                for (int k = 0; k < 4; k++) {
                    pk[k] = (unsigned)f2bf(di * acc[2 * k]) |
                            ((unsigned)f2bf(di * acc[2 * k + 1]) << 16);
                }
                *(v8s*)&sA[nloc * SROW + fl * 8] = *(v8s*)pk;
            }
        }
    }
    __syncthreads();

    // phase 2: 16x128 @ 128x128 MFMA (A from LDS, W bf16 from L2)
    v4f a0 = (v4f){0.f, 0.f, 0.f, 0.f};
    v4f a1 = (v4f){0.f, 0.f, 0.f, 0.f};
#pragma unroll
    for (int ks = 0; ks < 4; ks++) {
        v8s ah = *(const v8s*)&sA[(lane & 15) * SROW + ks * 32 + ((lane >> 4) << 3)];
        size_t bo0 = ((size_t)(ks * 8 + w * 2) * 64 + lane) * 8;
        size_t bo1 = ((size_t)(ks * 8 + w * 2 + 1) * 64 + lane) * 8;
        v8s bh0 = *(const v8s*)(Whi + bo0);
        v8s bh1 = *(const v8s*)(Whi + bo1);
        a0 = __builtin_amdgcn_mfma_f32_16x16x32_bf16(ah, bh0, a0, 0, 0, 0);
        a1 = __builtin_amdgcn_mfma_f32_16x16x32_bf16(ah, bh1, a1, 0, 0, 0);
    }
    __syncthreads();  // before reusing sA

    // epilogue: bias + relu (+ dinv unless last), LDS bounce, coalesced store
    float bb0 = bias[w * 32 + (lane & 15)];
    float bb1 = bias[w * 32 + 16 + (lane & 15)];
#pragma unroll
    for (int nt = 0; nt < 2; nt++) {
        int col_l = w * 32 + nt * 16 + (lane & 15);
        float bb = nt ? bb1 : bb0;
        v4f a = nt ? a1 : a0;
#pragma unroll
        for (int rg = 0; rg < 4; rg++) {
            int row_l = ((lane >> 4) << 2) + rg;
            float v = fmaxf(a[rg] + bb, 0.f);
            if (!last) v *= sDinv[row_l];
            sA[row_l * SROW + col_l] = f2bf(v);
        }
    }
    __syncthreads();
    int orow = tid >> 4;
    int ocol = (tid & 15) * 8;
    *(v8s*)(gout + (size_t)(row0 + orow) * FD + ocol) =
        *(const v8s*)&sA[orow * SROW + ocol];
}

// ---------- residual + classifier: out = (h + x) @ cls_w + cls_b ----------
__global__ __launch_bounds__(256) void k_cls(const unsigned short* __restrict__ h,
                                             const float* __restrict__ x,
                                             const float* __restrict__ cw,
                                             const float* __restrict__ cb,
                                             float* __restrict__ out) {
    int gw = (blockIdx.x * 256 + threadIdx.x) >> 6;
    int lane = threadIdx.x & 63;
    size_t o = (size_t)gw * FD + lane * 2;
    ushort2 hh = *(const ushort2*)(h + o);
    float2 xv = *(const float2*)(x + o);
    float sx = bf2f(hh.x) + xv.x;
    float sy = bf2f(hh.y) + xv.y;
    float4 w0 = *(const float4*)(cw + (lane * 2) * 4);
    float4 w1 = *(const float4*)(cw + (lane * 2 + 1) * 4);
    float p0 = sx * w0.x + sy * w1.x;
    float p1 = sx * w0.y + sy * w1.y;
    float p2 = sx * w0.z + sy * w1.z;
    float p3 = sx * w0.w + sy * w1.w;
#pragma unroll
    for (int off = 32; off > 0; off >>= 1) {
        p0 += __shfl_down(p0, off);
        p1 += __shfl_down(p1, off);
        p2 += __shfl_down(p2, off);
        p3 += __shfl_down(p3, off);
    }
    if (lane == 0) {
        float4 r2 = make_float4(p0 + cb[0], p1 + cb[1], p2 + cb[2], p3 + cb[3]);
        *(float4*)(out + (size_t)gw * 4) = r2;
    }
}

extern "C" void kernel_launch(void* const* d_in, const int* in_sizes, int n_in,
                              void* d_out, int out_size, void* d_ws, size_t ws_size,
                              hipStream_t stream) {
    const float* x       = (const float*)d_in[0];
    const int* ei        = (const int*)d_in[1];       // [2][EE], int32
    const float* weights = (const float*)d_in[2];
    const float* biases  = (const float*)d_in[3];
    const float* cls_w   = (const float*)d_in[4];
    const float* cls_b   = (const float*)d_in[5];
    float* out = (float*)d_out;

    char* ws = (char*)d_ws;
    size_t off = 0;
    auto alloc = [&](size_t bytes) -> void* {
        off = (off + 255) & ~(size_t)255;
        void* p = ws + off;
        off += bytes;
        return p;
    };
    int*   cnt    = (int*)alloc((size_t)NN * 4);
    int*   cursor = (int*)alloc((size_t)NN * 4);
    float* dinv   = (float*)alloc((size_t)NN * 4);
    int*   offs   = (int*)alloc((size_t)(NN + 1) * 4);
    int*   col    = (int*)alloc((size_t)EE * 4);
    unsigned short* Whi = (unsigned short*)alloc((size_t)NL * FD * FD * 2);
    unsigned short* h0  = (unsigned short*)alloc((size_t)NN * FD * 2);
    unsigned short* h1  = (unsigned short*)alloc((size_t)NN * FD * 2);

    const int* srcv = ei;
    const int* dstv = ei + EE;

    hipMemsetAsync(cnt, 0, (size_t)NN * 4, stream);
    hipMemsetAsync(cursor, 0, (size_t)NN * 4, stream);
    k_deg<<<EE / 256, 256, 0, stream>>>(dstv, cnt);
    k_dinv<<<NN / 256, 256, 0, stream>>>(cnt, dinv);
    k_scan<<<1, 1024, 0, stream>>>(cnt, offs);
    k_fill<<<EE / 256, 256, 0, stream>>>(srcv, dstv, offs, cursor, col);
    k_wcast<<<NL * 2048 / 256, 256, 0, stream>>>(weights, Whi);
    k_xcast<<<NN * FD / 2048, 256, 0, stream>>>(x, dinv, h1);  // g0 in h1

    const unsigned short* gin = h1;
    for (int l = 0; l < NL; l++) {
        unsigned short* gout = (l & 1) ? h1 : h0;
        k_layer<<<NN / MROW, 256, 0, stream>>>(gin, offs, col,
                                               Whi + (size_t)l * FD * FD,
                                               dinv, biases + (size_t)l * FD,
                                               gout, l == NL - 1);
        gin = gout;
    }
    k_cls<<<NN * 64 / 256, 256, 0, stream>>>(gin, x, cls_w, cls_b, out);
}

// Round 14
// 1015.669 us; speedup vs baseline: 1.5701x; 1.0894x over previous
//
#include <hip/hip_runtime.h>
#include <hip/hip_bf16.h>

#define NN 32768
#define EE 262144
#define FD 128
#define NL 64
#define MROW 16     // nodes per block — 2048 blocks, 8/CU, 32 waves/CU
#define SROW 132    // LDS row stride (ushorts)

typedef short v8s __attribute__((ext_vector_type(8)));
typedef float v4f __attribute__((ext_vector_type(4)));

__device__ __forceinline__ unsigned short f2bf(float x) {
    unsigned u = __builtin_bit_cast(unsigned, x);
    u += 0x7fffu + ((u >> 16) & 1u);
    return (unsigned short)(u >> 16);
}
__device__ __forceinline__ float bf2f(unsigned short h) {
    unsigned u = ((unsigned)h) << 16;
    return __builtin_bit_cast(float, u);
}
// accumulate 8 bf16 (packed in v8s) into acc[8]
__device__ __forceinline__ void acc8_bf16(float* acc, v8s r) {
    const int* d = (const int*)&r;
#pragma unroll
    for (int k = 0; k < 4; k++) {
        unsigned u = (unsigned)d[k];
        acc[2 * k]     += __builtin_bit_cast(float, u << 16);
        acc[2 * k + 1] += __builtin_bit_cast(float, u & 0xffff0000u);
    }
}

// ---------- setup ----------
__global__ __launch_bounds__(256) void k_deg(const int* __restrict__ dst,
                                             int* __restrict__ cnt) {
    int e = blockIdx.x * 256 + threadIdx.x;
    if (e < EE) atomicAdd(&cnt[dst[e]], 1);
}

__global__ __launch_bounds__(256) void k_dinv(const int* __restrict__ cnt,
                                              float* __restrict__ dinv) {
    int i = blockIdx.x * 256 + threadIdx.x;
    if (i < NN) dinv[i] = rsqrtf((float)cnt[i] + 1.0f);
}

// hierarchical scan (R11 profile: the old single-block scan alone cost ~51us)
// stage A: 128 blocks x 256 thr -> per-block sums
__global__ __launch_bounds__(256) void k_scanA(const int* __restrict__ cnt,
                                               int* __restrict__ bsum) {
    __shared__ int ws[4];
    int tid = threadIdx.x;
    int v = cnt[blockIdx.x * 256 + tid];
    int x = v;
#pragma unroll
    for (int off = 1; off < 64; off <<= 1) x += __shfl_xor(x, off);
    if ((tid & 63) == 0) ws[tid >> 6] = x;
    __syncthreads();
    if (tid == 0) bsum[blockIdx.x] = ws[0] + ws[1] + ws[2] + ws[3];
}
// stage B: 1 block x 128 thr -> exclusive scan of block sums (+ total)
__global__ __launch_bounds__(128) void k_scanB(const int* __restrict__ bsum,
                                               int* __restrict__ boff,
                                               int* __restrict__ offs) {
    __shared__ int s0;
    int tid = threadIdx.x;
    int v = bsum[tid];
    int lane = tid & 63, w = tid >> 6;
    int x = v;
#pragma unroll
    for (int off = 1; off < 64; off <<= 1) {
        int y = __shfl_up(x, off);
        if (lane >= off) x += y;
    }
    if (tid == 63) s0 = x;
    __syncthreads();
    int excl = x - v + (w ? s0 : 0);
    boff[tid] = excl;
    if (tid == 127) offs[NN] = excl + v;
}
// stage C: 128 blocks x 256 thr -> final exclusive scan
__global__ __launch_bounds__(256) void k_scanC(const int* __restrict__ cnt,
                                               const int* __restrict__ boff,
                                               int* __restrict__ offs) {
    __shared__ int ws[4];
    int tid = threadIdx.x;
    int i = blockIdx.x * 256 + tid;
    int v = cnt[i];
    int lane = tid & 63, w = tid >> 6;
    int x = v;
#pragma unroll
    for (int off = 1; off < 64; off <<= 1) {
        int y = __shfl_up(x, off);
        if (lane >= off) x += y;
    }
    if (lane == 63) ws[w] = x;
    __syncthreads();
    int wexcl = 0;
#pragma unroll
    for (int k = 0; k < 4; k++) if (k < w) wexcl += ws[k];
    offs[i] = boff[blockIdx.x] + wexcl + x - v;
}

__global__ __launch_bounds__(256) void k_fill(const int* __restrict__ src,
                                              const int* __restrict__ dst,
                                              const int* __restrict__ offs,
                                              int* __restrict__ cursor,
                                              int* __restrict__ col) {
    int e = blockIdx.x * 256 + threadIdx.x;
    if (e >= EE) return;
    int s = src[e], d = dst[e];
    int slot = atomicAdd(&cursor[d], 1);
    col[offs[d] + slot] = s;
}

// g0 = bf16(dinv[node] * x)
__global__ __launch_bounds__(256) void k_xcast(const float* __restrict__ x,
                                               const float* __restrict__ dinv,
                                               unsigned short* __restrict__ g) {
    int i = blockIdx.x * 256 + threadIdx.x;
    float di = dinv[(i * 8) >> 7];
    float4 a = *(const float4*)(x + (size_t)i * 8);
    float4 b = *(const float4*)(x + (size_t)i * 8 + 4);
    v8s o;
    o[0] = (short)f2bf(di * a.x); o[1] = (short)f2bf(di * a.y);
    o[2] = (short)f2bf(di * a.z); o[3] = (short)f2bf(di * a.w);
    o[4] = (short)f2bf(di * b.x); o[5] = (short)f2bf(di * b.y);
    o[6] = (short)f2bf(di * b.z); o[7] = (short)f2bf(di * b.w);
    *(v8s*)(g + (size_t)i * 8) = o;
}

// ---------- weight cast: fp32 W -> bf16 in MFMA B-fragment order ----------
// [l][kstep(4)][ntile(8)][lane(64)][j(8)]; k = ks*32+(lane>>4)*8+j, n = nt*16+(lane&15)
__global__ __launch_bounds__(256) void k_wcast(const float* __restrict__ W,
                                               unsigned short* __restrict__ Whi) {
    int t = blockIdx.x * 256 + threadIdx.x;
    int l = t >> 11;
    int rem = t & 2047;
    int ks = rem >> 9;
    int rem2 = rem & 511;
    int nt = rem2 >> 6;
    int L = rem2 & 63;
    const float* Wl = W + (size_t)l * FD * FD;
    int kbase = ks * 32 + ((L >> 4) << 3);
    int n = nt * 16 + (L & 15);
    v8s hv;
#pragma unroll
    for (int j = 0; j < 8; j++)
        hv[j] = (short)f2bf(Wl[(size_t)(kbase + j) * FD + n]);
    *(v8s*)(Whi + (size_t)t * 8) = hv;
}

// ---------- fused layer: g_out = dinv * relu( (dinv*(sum g)) @ W + b ) ----
// Phase 1: one 16-lane group per node; node-private acc (no cross-lane
// reduce); 6-deep unrolled predicated gather (self row loaded post-loop to
// stay inside the 64-VGPR budget at 8 waves/SIMD).
__global__ __launch_bounds__(256, 8) void k_layer(
        const unsigned short* __restrict__ g,
        const int* __restrict__ offs,
        const int* __restrict__ col,
        const unsigned short* __restrict__ Whi,
        const float* __restrict__ dinv,
        const float* __restrict__ bias,
        unsigned short* __restrict__ gout,
        int last) {
    __shared__ unsigned short sA[MROW * SROW];
    __shared__ float sDinv[MROW];
    int tid = threadIdx.x;
    int lane = tid & 63;
    int w = tid >> 6;
    int row0 = blockIdx.x * MROW;
    int fg = lane >> 4;        // node subgroup 0..3 (one node per group)
    int fl = lane & 15;        // feature chunk (8 feats = 16B)
    const unsigned short* gf = g + fl * 8;

    if (tid < MROW) sDinv[tid] = dinv[row0 + tid];

    int nbase = row0 + w * 4;                      // multiple of 4 -> aligned
    int4 ov = *(const int4*)(offs + nbase);
    int o4 = offs[nbase + 4];
    int B0 = ov.x;
    int Etot = o4 - B0;

    if (Etot <= 64) {
        // fast path: one coalesced col window covers all 4 nodes
        int c = (lane < Etot) ? col[B0 + lane] : 0;
        int node = nbase + fg;
        int sg = ((fg == 0) ? ov.x : (fg == 1) ? ov.y : (fg == 2) ? ov.z : ov.w) - B0;
        int eg = ((fg == 0) ? ov.y : (fg == 1) ? ov.z : (fg == 2) ? ov.w : o4) - B0;
        int len = eg - sg;
        int m = max(len, __shfl_xor(len, 16));
        m = max(m, __shfl_xor(m, 32));      // max deg over the 4 groups
        float acc[8];
#pragma unroll
        for (int k = 0; k < 8; k++) acc[k] = 0.f;
        for (int j = 0; j < m; j += 6) {
            int i0 = sg + j,     i1 = sg + j + 1, i2 = sg + j + 2;
            int i3 = sg + j + 3, i4 = sg + j + 4, i5 = sg + j + 5;
            bool p0 = i0 < eg, p1 = i1 < eg, p2 = i2 < eg;
            bool p3 = i3 < eg, p4 = i4 < eg, p5 = i5 < eg;
            int s0 = __shfl(c, i0 & 63);
            int s1 = __shfl(c, i1 & 63);
            int s2 = __shfl(c, i2 & 63);
            int s3 = __shfl(c, i3 & 63);
            int s4 = __shfl(c, i4 & 63);
            int s5 = __shfl(c, i5 & 63);
            v8s r0, r1, r2, r3, r4, r5;
            if (p0) r0 = *(const v8s*)(gf + (size_t)s0 * FD);
            if (p1) r1 = *(const v8s*)(gf + (size_t)s1 * FD);
            if (p2) r2 = *(const v8s*)(gf + (size_t)s2 * FD);
            if (p3) r3 = *(const v8s*)(gf + (size_t)s3 * FD);
            if (p4) r4 = *(const v8s*)(gf + (size_t)s4 * FD);
            if (p5) r5 = *(const v8s*)(gf + (size_t)s5 * FD);
            if (p0) acc8_bf16(acc, r0);
            if (p1) acc8_bf16(acc, r1);
            if (p2) acc8_bf16(acc, r2);
            if (p3) acc8_bf16(acc, r3);
            if (p4) acc8_bf16(acc, r4);
            if (p5) acc8_bf16(acc, r5);
        }
        v8s selfv = *(const v8s*)(gf + (size_t)node * FD);
        acc8_bf16(acc, selfv);   // self loop
        float di = dinv[node];
        unsigned pk[4];
#pragma unroll
        for (int k = 0; k < 4; k++) {
            pk[k] = (unsigned)f2bf(di * acc[2 * k]) |
                    ((unsigned)f2bf(di * acc[2 * k + 1]) << 16);
        }
        *(v8s*)&sA[(w * 4 + fg) * SROW + fl * 8] = *(v8s*)pk;  // all lanes write
    } else {
        // rare path: per-node col loads, any degree
        for (int r = 0; r < 4; r++) {
            int nloc = w * 4 + r;
            int node = row0 + nloc;
            float acc[8];
#pragma unroll
            for (int k = 0; k < 8; k++) acc[k] = 0.f;
            int b = offs[node], e = offs[node + 1];
            int deg = e - b;
            for (int base = 0; base < deg; base += 64) {
                int n = min(deg - base, 64);
                int c = (lane < n) ? col[b + base + lane] : 0;
                for (int j = 0; j < n; j += 8) {
                    int e0 = j + fg, e1 = j + 4 + fg;
                    int s0 = __shfl(c, e0 & 63);
                    int s1 = __shfl(c, e1 & 63);
                    bool p0 = e0 < n, p1 = e1 < n;
                    v8s r0, r1;
                    if (p0) r0 = *(const v8s*)(gf + (size_t)s0 * FD);
                    if (p1) r1 = *(const v8s*)(gf + (size_t)s1 * FD);
                    if (p0) acc8_bf16(acc, r0);
                    if (p1) acc8_bf16(acc, r1);
                }
            }
#pragma unroll
            for (int k = 0; k < 8; k++) {
                acc[k] += __shfl_xor(acc[k], 16);
                acc[k] += __shfl_xor(acc[k], 32);
            }
            v8s sv = *(const v8s*)(gf + (size_t)node * FD);
            acc8_bf16(acc, sv);
            if (fg == 0) {
                float di = dinv[node];
                unsigned pk[4];
#pragma unroll
                for (int k = 0; k < 4; k++) {
                    pk[k] = (unsigned)f2bf(di * acc[2 * k]) |
                            ((unsigned)f2bf(di * acc[2 * k + 1]) << 16);
                }
                *(v8s*)&sA[nloc * SROW + fl * 8] = *(v8s*)pk;
            }
        }
    }
    __syncthreads();

    // phase 2: 16x128 @ 128x128 MFMA (A from LDS, W bf16 from L2)
    v4f a0 = (v4f){0.f, 0.f, 0.f, 0.f};
    v4f a1 = (v4f){0.f, 0.f, 0.f, 0.f};
#pragma unroll
    for (int ks = 0; ks < 4; ks++) {
        v8s ah = *(const v8s*)&sA[(lane & 15) * SROW + ks * 32 + ((lane >> 4) << 3)];
        size_t bo0 = ((size_t)(ks * 8 + w * 2) * 64 + lane) * 8;
        size_t bo1 = ((size_t)(ks * 8 + w * 2 + 1) * 64 + lane) * 8;
        v8s bh0 = *(const v8s*)(Whi + bo0);
        v8s bh1 = *(const v8s*)(Whi + bo1);
        a0 = __builtin_amdgcn_mfma_f32_16x16x32_bf16(ah, bh0, a0, 0, 0, 0);
        a1 = __builtin_amdgcn_mfma_f32_16x16x32_bf16(ah, bh1, a1, 0, 0, 0);
    }
    __syncthreads();  // before reusing sA

    // epilogue: bias + relu (+ dinv unless last), LDS bounce, coalesced store
    float bb0 = bias[w * 32 + (lane & 15)];
    float bb1 = bias[w * 32 + 16 + (lane & 15)];
#pragma unroll
    for (int nt = 0; nt < 2; nt++) {
        int col_l = w * 32 + nt * 16 + (lane & 15);
        float bb = nt ? bb1 : bb0;
        v4f a = nt ? a1 : a0;
#pragma unroll
        for (int rg = 0; rg < 4; rg++) {
            int row_l = ((lane >> 4) << 2) + rg;
            float v = fmaxf(a[rg] + bb, 0.f);
            if (!last) v *= sDinv[row_l];
            sA[row_l * SROW + col_l] = f2bf(v);
        }
    }
    __syncthreads();
    int orow = tid >> 4;
    int ocol = (tid & 15) * 8;
    *(v8s*)(gout + (size_t)(row0 + orow) * FD + ocol) =
        *(const v8s*)&sA[orow * SROW + ocol];
}

// ---------- residual + classifier: out = (h + x) @ cls_w + cls_b ----------
__global__ __launch_bounds__(256) void k_cls(const unsigned short* __restrict__ h,
                                             const float* __restrict__ x,
                                             const float* __restrict__ cw,
                                             const float* __restrict__ cb,
                                             float* __restrict__ out) {
    int gw = (blockIdx.x * 256 + threadIdx.x) >> 6;
    int lane = threadIdx.x & 63;
    size_t o = (size_t)gw * FD + lane * 2;
    ushort2 hh = *(const ushort2*)(h + o);
    float2 xv = *(const float2*)(x + o);
    float sx = bf2f(hh.x) + xv.x;
    float sy = bf2f(hh.y) + xv.y;
    float4 w0 = *(const float4*)(cw + (lane * 2) * 4);
    float4 w1 = *(const float4*)(cw + (lane * 2 + 1) * 4);
    float p0 = sx * w0.x + sy * w1.x;
    float p1 = sx * w0.y + sy * w1.y;
    float p2 = sx * w0.z + sy * w1.z;
    float p3 = sx * w0.w + sy * w1.w;
#pragma unroll
    for (int off = 32; off > 0; off >>= 1) {
        p0 += __shfl_down(p0, off);
        p1 += __shfl_down(p1, off);
        p2 += __shfl_down(p2, off);
        p3 += __shfl_down(p3, off);
    }
    if (lane == 0) {
        float4 r2 = make_float4(p0 + cb[0], p1 + cb[1], p2 + cb[2], p3 + cb[3]);
        *(float4*)(out + (size_t)gw * 4) = r2;
    }
}

extern "C" void kernel_launch(void* const* d_in, const int* in_sizes, int n_in,
                              void* d_out, int out_size, void* d_ws, size_t ws_size,
                              hipStream_t stream) {
    const float* x       = (const float*)d_in[0];
    const int* ei        = (const int*)d_in[1];       // [2][EE], int32
    const float* weights = (const float*)d_in[2];
    const float* biases  = (const float*)d_in[3];
    const float* cls_w   = (const float*)d_in[4];
    const float* cls_b   = (const float*)d_in[5];
    float* out = (float*)d_out;

    char* ws = (char*)d_ws;
    size_t off = 0;
    auto alloc = [&](size_t bytes) -> void* {
        off = (off + 255) & ~(size_t)255;
        void* p = ws + off;
        off += bytes;
        return p;
    };
    int*   cnt    = (int*)alloc((size_t)NN * 4);
    int*   cursor = (int*)alloc((size_t)NN * 4);
    float* dinv   = (float*)alloc((size_t)NN * 4);
    int*   offs   = (int*)alloc((size_t)(NN + 1) * 4);
    int*   bsum   = (int*)alloc((size_t)128 * 4);
    int*   boff   = (int*)alloc((size_t)128 * 4);
    int*   col    = (int*)alloc((size_t)EE * 4);
    unsigned short* Whi = (unsigned short*)alloc((size_t)NL * FD * FD * 2);
    unsigned short* h0  = (unsigned short*)alloc((size_t)NN * FD * 2);
    unsigned short* h1  = (unsigned short*)alloc((size_t)NN * FD * 2);

    const int* srcv = ei;
    const int* dstv = ei + EE;

    hipMemsetAsync(cnt, 0, (size_t)NN * 4, stream);
    hipMemsetAsync(cursor, 0, (size_t)NN * 4, stream);
    k_deg<<<EE / 256, 256, 0, stream>>>(dstv, cnt);
    k_dinv<<<NN / 256, 256, 0, stream>>>(cnt, dinv);
    k_scanA<<<128, 256, 0, stream>>>(cnt, bsum);
    k_scanB<<<1, 128, 0, stream>>>(bsum, boff, offs);
    k_scanC<<<128, 256, 0, stream>>>(cnt, boff, offs);
    k_fill<<<EE / 256, 256, 0, stream>>>(srcv, dstv, offs, cursor, col);
    k_wcast<<<NL * 2048 / 256, 256, 0, stream>>>(weights, Whi);
    k_xcast<<<NN * FD / 2048, 256, 0, stream>>>(x, dinv, h1);  // g0 in h1

    const unsigned short* gin = h1;
    for (int l = 0; l < NL; l++) {
        unsigned short* gout = (l & 1) ? h1 : h0;
        k_layer<<<NN / MROW, 256, 0, stream>>>(gin, offs, col,
                                               Whi + (size_t)l * FD * FD,
                                               dinv, biases + (size_t)l * FD,
                                               gout, l == NL - 1);
        gin = gout;
    }
    k_cls<<<NN * 64 / 256, 256, 0, stream>>>(gin, x, cls_w, cls_b, out);
}